// Round 2
// baseline (1565.381 us; speedup 1.0000x reference)
//
#include <hip/hip_runtime.h>

// LSTMModel: 4-layer LSTM (H=50, IN=7, B=1024, T=512) + FC(50->25 relu ->1).
// R2: MFMA formulation. Per layer-tick: gates[256pad x 16] = A[256 x 128] * B[128 x 16]
// via mfma_f32_16x16x32_f16. A = weights (resident in VGPRs as fragments),
// B = [input_h(64 slots) ; own_h(64 slots)] in LDS, N cols = batch (4 of 16 used).
// Gate rows interleaved (unit-major: rows 4u+{i,f,g,o}) so C-layout rows are
// contiguous float4 per (unit,b) -> staged fp32 to LDS -> 800 dedicated update
// threads (c-state in VGPR) -> h written back to LDS as f16 at permuted slots.
// K-slot permutation pi(16w+4t+q) = 16w+4q+t (involution) makes each update
// thread's h slot scalar-addressable while A-frag loads use pi to find weights.

#define H 50
#define INSZ 7
#define BATCH 1024
#define TT 512
#define NL 4
#define FC1N 25
#define BPG 4
#define NBLK (BATCH / BPG)
#define NTHREADS 1024
#define KP 136    // Bbuf row stride in halves (272 B: 16B-aligned, bank-stride 4)
#define GLDSP 260 // glds row stride in floats (bank-stride 4)

typedef _Float16 half_t;
typedef __attribute__((ext_vector_type(8))) _Float16 half8_t;
typedef __attribute__((ext_vector_type(4))) float float4_t;

struct Params {
  const float* x;
  const float* Wih[NL];
  const float* Whh[NL];
  const float* bih[NL];
  const float* bhh[NL];
  const float* W1;
  const float* b1;
  const float* W2;
  const float* b2;
  float* out;
};

// involution: swap the two 2-bit fields below bit 4
__device__ __forceinline__ int kperm(int s) {
  return (s & ~15) | ((s & 3) << 2) | ((s >> 2) & 3);
}

__device__ __forceinline__ float sigf(float x) { return 1.0f / (1.0f + __expf(-x)); }
__device__ __forceinline__ float tanh_fast(float x) { return 2.0f * sigf(2.0f * x) - 1.0f; }

__global__ __launch_bounds__(NTHREADS) void lstm_mfma(Params p) {
  __shared__ __align__(16) half_t Bbuf[NL][16][KP];   // [layer][n(batch,16 rows)][k slot]
  __shared__ __align__(16) float glds[NL][BPG][GLDSP]; // gate preacts, row = 4u+q
  __shared__ float fc_h[BPG][H];
  __shared__ float fc1_buf[BPG][FC1N];

  const int tid = threadIdx.x;
  const int b0 = blockIdx.x * BPG;
  const int lane = tid & 63;
  const int quad = lane >> 4;
  const int col = lane & 15;
  const int glay = tid >> 8;        // gate-role layer (4 waves each)
  const int wl = (tid >> 6) & 3;    // wave within layer

  // update role: tid < 800 -> (ulay, ubb, uu), u fastest for coalesced glds reads
  const bool is_upd = tid < NL * BPG * H;
  const int ulay = tid / (BPG * H);
  const int urem = tid % (BPG * H);
  const int ubb = urem / H;
  const int uu = urem % H;

  // x-prefetch role: tids [960, 988) (layer-3 wl-3 wave: lightest gate load)
  const int lt = tid - 960;
  const bool is_load = (lt >= 0) && (lt < BPG * INSZ);
  const int lb = is_load ? lt / INSZ : 0;
  const int lk = is_load ? lt % INSZ : 0;

  // ---- load A fragments (weights, f16) + bias (f32) into registers ----
  // A[r][k]: r = wl*64 + t*16 + (lane&15), k = ks*32 + quad*8 + j
  // row r -> unit u=r>>2, gate q=r&3 -> original gate row g = q*H + u
  // k<64: input section (layer0: x at k<7; else h_{l-1} at slot k -> unit kperm(k))
  // k>=64: own-h section (slot k-64 -> unit kperm(k-64))
  half8_t afrag[4][4];
  float bias[4][4];
  for (int t = 0; t < 4; ++t) {
    for (int ks = 0; ks < 4; ++ks) {
      half8_t v;
#pragma unroll
      for (int j = 0; j < 8; ++j) {
        const int k = ks * 32 + quad * 8 + j;
        const int r = wl * 64 + t * 16 + col;
        const int u = r >> 2, q = r & 3;
        float wv = 0.0f;
        if (u < H) {
          const int g = q * H + u;
          if (k < 64) {
            if (glay == 0) {
              if (k < INSZ) wv = p.Wih[0][g * INSZ + k];
            } else {
              const int ui = kperm(k);
              if (ui < H) wv = p.Wih[glay][g * H + ui];
            }
          } else {
            const int uh = kperm(k - 64);
            if (uh < H) wv = p.Whh[glay][g * H + uh];
          }
        }
        v[j] = (half_t)wv;
      }
      afrag[t][ks] = v;
    }
#pragma unroll
    for (int pp = 0; pp < 4; ++pp) {
      const int r = wl * 64 + t * 16 + quad * 4 + pp;
      const int u = r >> 2, q = r & 3;
      bias[t][pp] = (u < H) ? (p.bih[glay][q * H + u] + p.bhh[glay][q * H + u]) : 0.0f;
    }
  }

  // ---- zero Bbuf (unwritten slots must be 0.0, never NaN, for mfma) ----
  for (int i = tid; i < NL * 16 * KP; i += NTHREADS) ((half_t*)Bbuf)[i] = (half_t)0.0f;
  __syncthreads();
  if (tid < BPG * INSZ) {  // preload x(t=0)
    const int b = tid / INSZ, k = tid % INSZ;
    Bbuf[0][b][k] = (half_t)p.x[((size_t)(b0 + b) * TT + 0) * INSZ + k];
  }
  __syncthreads();

  const half_t* bfp = &Bbuf[glay][col][quad * 8];
  float cstate = 0.0f;

  for (int s = 0; s < TT + NL - 1; ++s) {
    // x prefetch for t = s+1 (latency hidden behind gate phase)
    float xreg = 0.0f;
    if (is_load && (s + 1) < TT)
      xreg = p.x[((size_t)(b0 + lb) * TT + (s + 1)) * INSZ + lk];

    // ---- gate phase: mfma, stage preacts to glds ----
    const int tg = s - glay;
    if (tg >= 0 && tg < TT) {
      float4_t acc[4];
#pragma unroll
      for (int t = 0; t < 4; ++t) {
        float4_t a = {bias[t][0], bias[t][1], bias[t][2], bias[t][3]};
        acc[t] = a;
      }
#pragma unroll
      for (int ks = 0; ks < 4; ++ks) {
        if (glay == 0 && ks == 1) continue;  // layer0: k 32..63 all-zero A
        const half8_t bf = *(const half8_t*)(bfp + ks * 32);
#pragma unroll
        for (int t = 0; t < 4; ++t) {
          if (16 * wl + 4 * t < H)  // tile has at least one valid unit
            acc[t] = __builtin_amdgcn_mfma_f32_16x16x32_f16(afrag[t][ks], bf, acc[t], 0, 0, 0);
        }
      }
      if (col < BPG) {
#pragma unroll
        for (int t = 0; t < 4; ++t) {
          if (16 * wl + 4 * t < H)
            *(float4_t*)&glds[glay][col][wl * 64 + t * 16 + quad * 4] = acc[t];
        }
      }
    }
    __syncthreads();

    // ---- update phase: dedicated threads, c in VGPR ----
    const int tu = s - ulay;
    if (is_upd && tu >= 0 && tu < TT) {
      const float4_t gv = *(const float4_t*)&glds[ulay][ubb][4 * uu];
      const float gi = sigf(gv[0]);
      const float gf = sigf(gv[1]);
      const float gg = tanh_fast(gv[2]);
      const float go = sigf(gv[3]);
      cstate = gf * cstate + gi * gg;
      const float h = go * tanh_fast(cstate);
      const half_t hh = (half_t)h;
      const int slot = kperm(uu);
      Bbuf[ulay][ubb][64 + slot] = hh;                 // own-h for next t
      if (ulay < NL - 1) Bbuf[ulay + 1][ubb][slot] = hh;  // input-h for layer above
      if (ulay == NL - 1 && tu == TT - 1) fc_h[ubb][uu] = h;
    }
    if (is_load && (s + 1) < TT) Bbuf[0][lb][lk] = (half_t)xreg;
    __syncthreads();
  }

  // ---- FC head (fp32) ----
  if (tid < BPG * FC1N) {
    const int b = tid / FC1N, j = tid % FC1N;
    const float* w = p.W1 + j * H;
    float a = p.b1[j];
#pragma unroll
    for (int k = 0; k < H; ++k) a += fc_h[b][k] * w[k];
    fc1_buf[b][j] = fmaxf(a, 0.0f);
  }
  __syncthreads();
  if (tid < BPG) {
    float a = p.b2[0];
#pragma unroll
    for (int j = 0; j < FC1N; ++j) a += fc1_buf[tid][j] * p.W2[j];
    p.out[b0 + tid] = a;
  }
}

extern "C" void kernel_launch(void* const* d_in, const int* in_sizes, int n_in,
                              void* d_out, int out_size, void* d_ws, size_t ws_size,
                              hipStream_t stream) {
  Params p;
  p.x = (const float*)d_in[0];
  for (int l = 0; l < NL; ++l) {
    p.Wih[l] = (const float*)d_in[1 + 4 * l];
    p.Whh[l] = (const float*)d_in[2 + 4 * l];
    p.bih[l] = (const float*)d_in[3 + 4 * l];
    p.bhh[l] = (const float*)d_in[4 + 4 * l];
  }
  p.W1 = (const float*)d_in[17];
  p.b1 = (const float*)d_in[18];
  p.W2 = (const float*)d_in[19];
  p.b2 = (const float*)d_in[20];
  p.out = (float*)d_out;

  hipLaunchKernelGGL(lstm_mfma, dim3(NBLK), dim3(NTHREADS), 0, stream, p);
}

// Round 3
// 1006.449 us; speedup vs baseline: 1.5554x; 1.5554x over previous
//
#include <hip/hip_runtime.h>

// LSTMModel: 4-layer LSTM (H=50, IN=7, B=1024, T=512) + FC(50->25 relu ->1).
// R3: fix R2's VGPR spill (launch_bounds(1024,4) -> cap 128; bias folded into
// a constant-1.0 B slot so no bias VGPRs). One barrier per tick: cell update
// done IN-WAVE from MFMA C-regs (C layout: lane(quad,col) holds gates i,f,g,o
// of unit 16wl+4t+quad, batch col in acc[t][0..3]). Batch replicated 2x in B
// cols (cols 0-7 = 2 copies of 4 batches) so each lane updates 2 units.
// B per layer is parity-double-buffered: reads from parity t&1, writes to
// t^1 parity -> no intra-tick races, 1 barrier. Slot map
// u=16w+4t+q -> 16w+4q+2(t&1)+(t>>1) makes each lane's 2 h values adjacent
// (one packed half2 write per destination).

#define H 50
#define INSZ 7
#define BATCH 1024
#define TT 512
#define NL 4
#define FC1N 25
#define BPG 4
#define NBLK (BATCH / BPG)
#define NTHREADS 1024
#define KP 136        // Bbuf row stride in halves (272 B; bank stride 4, 2-way max)
#define ROWS 16
#define SEC_OWN 64    // own-h section offset (halves)
#define BIAS_SLOT_L 63
#define BIAS_SLOT_0 7

typedef _Float16 half_t;
typedef __attribute__((ext_vector_type(2))) _Float16 half2_t;
typedef __attribute__((ext_vector_type(8))) _Float16 half8_t;
typedef __attribute__((ext_vector_type(4))) float float4_t;

struct Params {
  const float* x;
  const float* Wih[NL];
  const float* Whh[NL];
  const float* bih[NL];
  const float* bhh[NL];
  const float* W1;
  const float* b1;
  const float* W2;
  const float* b2;
  float* out;
};

// slot s -> unit: inverse of u=16w+4t+q -> slot 16w+4q+2*(t&1)+(t>>1)
__device__ __forceinline__ int smap_u(int s) {
  const int w = s >> 4, q = (s >> 2) & 3, o = s & 3;
  const int t = ((o & 1) << 1) | (o >> 1);
  return 16 * w + 4 * t + q;
}

__device__ __forceinline__ float sigf(float x) { return 1.0f / (1.0f + __expf(-x)); }
__device__ __forceinline__ float tanh_fast(float x) { return 2.0f * sigf(2.0f * x) - 1.0f; }

__global__ __launch_bounds__(NTHREADS, 4) void lstm_r3(Params p) {
  __shared__ __align__(16) half_t Bbuf[NL][2][ROWS][KP];
  __shared__ float fc_h[BPG][H];
  __shared__ float fc1_buf[BPG][FC1N];

  const int tid = threadIdx.x;
  const int b0 = blockIdx.x * BPG;
  const int lane = tid & 63;
  const int quad = lane >> 4;
  const int col = lane & 15;
  const int glay = tid >> 8;       // 4 waves per layer
  const int wl = (tid >> 6) & 3;   // wave within layer

  // ---- A fragments (weights + bias column), resident in VGPRs ----
  // A[m][k] fragment: m = col (row r = wl*64 + 16t + col), k = g*32 + quad*8 + j
  // row r -> unit u = r>>2, gate q = r&3 (rows unit-major: r = 4u+q)
  half8_t afrag[4][4];
#pragma unroll
  for (int t = 0; t < 4; ++t) {
#pragma unroll
    for (int g = 0; g < 4; ++g) {
      half8_t v;
#pragma unroll
      for (int j = 0; j < 8; ++j) {
        const int r = wl * 64 + t * 16 + col;
        const int u = r >> 2, q = r & 3;
        float wv = 0.0f;
        if (u < H) {
          const int row = q * H + u;
          if (glay == 0) {
            if (g == 0) {
              const int s = quad * 8 + j;
              if (s < INSZ) wv = p.Wih[0][row * INSZ + s];
              else if (s == BIAS_SLOT_0) wv = p.bih[0][row] + p.bhh[0][row];
            } else if (g <= 2) {
              const int s = (g - 1) * 32 + quad * 8 + j;
              const int us = smap_u(s);
              if (us < H) wv = p.Whh[0][row * H + us];
            }
          } else {
            const int k = g * 32 + quad * 8 + j;
            if (k < 64) {
              if (k == BIAS_SLOT_L) wv = p.bih[glay][row] + p.bhh[glay][row];
              else { const int us = smap_u(k); if (us < H) wv = p.Wih[glay][row * H + us]; }
            } else {
              const int us = smap_u(k - 64);
              if (us < H) wv = p.Whh[glay][row * H + us];
            }
          }
        }
        v[j] = (half_t)wv;
      }
      afrag[t][g] = v;
    }
  }

  // ---- zero Bbuf, set bias-1.0 slots, preload x(t=0) ----
  {
    unsigned* bz = (unsigned*)Bbuf;
    const int nw = NL * 2 * ROWS * KP / 2;
    for (int i = tid; i < nw; i += NTHREADS) bz[i] = 0u;
  }
  __syncthreads();
  if (tid < 64) {  // bias slots: all layers, both parities, rows 0..7
    const int pp = tid & 1, row = (tid >> 1) & 7, l = tid >> 4;
    Bbuf[l][pp][row][(l == 0) ? BIAS_SLOT_0 : BIAS_SLOT_L] = (half_t)1.0f;
  }
  if (tid >= 64 && tid < 64 + BPG * INSZ) {
    const int idx = tid - 64, b = idx / INSZ, k = idx % INSZ;
    const half_t xh = (half_t)p.x[((size_t)(b0 + b) * TT + 0) * INSZ + k];
    Bbuf[0][0][b][k] = xh;
    Bbuf[0][0][b + 4][k] = xh;
  }
  __syncthreads();

  // ---- per-lane update-role constants ----
  const int jl = (col >> 2) & 1;        // replication copy (valid for col<8)
  const int bb = col & 3;
  const int u0 = 16 * wl + 4 * jl + quad;   // unit for t=jl
  const int u1 = u0 + 8;                    // unit for t=jl+2
  const int sbase = 16 * wl + 4 * quad + 2 * jl;
  const bool updlane = (col < 8) && (u0 < H);

  // x prefetch role: idle cols 8..15 of layer-0/wl-0 wave
  const int xidx = quad * 8 + (col - 8);
  const bool xact = (glay == 0) && (wl == 0) && (col >= 8) && (xidx < BPG * INSZ);
  const int xb = xidx / INSZ, xk = xidx % INSZ;

  float c0 = 0.0f, c1 = 0.0f;
  const float4_t fz = {0.0f, 0.0f, 0.0f, 0.0f};

  // ---- main loop: one barrier per tick ----
  for (int s = 0; s < TT + NL - 1; ++s) {
    const int t = s - glay;
    const bool act = (t >= 0) && (t < TT);

    float xv = 0.0f;
    if (xact && (s + 1) < TT)
      xv = p.x[((size_t)(b0 + xb) * TT + (s + 1)) * INSZ + xk];

    if (act) {
      const int par = t & 1;
      const half_t* base = &Bbuf[glay][par][col][0];
      float4_t a0, a1, a2, a3;
      if (glay == 0) {
        const half8_t v0 = *(const half8_t*)(base + quad * 8);
        const half8_t v2 = *(const half8_t*)(base + SEC_OWN + quad * 8);
        const half8_t v3 = *(const half8_t*)(base + SEC_OWN + 32 + quad * 8);
        a0 = __builtin_amdgcn_mfma_f32_16x16x32_f16(afrag[0][0], v0, fz, 0, 0, 0);
        a1 = __builtin_amdgcn_mfma_f32_16x16x32_f16(afrag[1][0], v0, fz, 0, 0, 0);
        a2 = __builtin_amdgcn_mfma_f32_16x16x32_f16(afrag[2][0], v0, fz, 0, 0, 0);
        a3 = __builtin_amdgcn_mfma_f32_16x16x32_f16(afrag[3][0], v0, fz, 0, 0, 0);
        a0 = __builtin_amdgcn_mfma_f32_16x16x32_f16(afrag[0][1], v2, a0, 0, 0, 0);
        a1 = __builtin_amdgcn_mfma_f32_16x16x32_f16(afrag[1][1], v2, a1, 0, 0, 0);
        a2 = __builtin_amdgcn_mfma_f32_16x16x32_f16(afrag[2][1], v2, a2, 0, 0, 0);
        a3 = __builtin_amdgcn_mfma_f32_16x16x32_f16(afrag[3][1], v2, a3, 0, 0, 0);
        a0 = __builtin_amdgcn_mfma_f32_16x16x32_f16(afrag[0][2], v3, a0, 0, 0, 0);
        a1 = __builtin_amdgcn_mfma_f32_16x16x32_f16(afrag[1][2], v3, a1, 0, 0, 0);
        a2 = __builtin_amdgcn_mfma_f32_16x16x32_f16(afrag[2][2], v3, a2, 0, 0, 0);
        a3 = __builtin_amdgcn_mfma_f32_16x16x32_f16(afrag[3][2], v3, a3, 0, 0, 0);
      } else {
        const half8_t v0 = *(const half8_t*)(base + quad * 8);
        const half8_t v1 = *(const half8_t*)(base + 32 + quad * 8);
        const half8_t v2 = *(const half8_t*)(base + SEC_OWN + quad * 8);
        const half8_t v3 = *(const half8_t*)(base + SEC_OWN + 32 + quad * 8);
        a0 = __builtin_amdgcn_mfma_f32_16x16x32_f16(afrag[0][0], v0, fz, 0, 0, 0);
        a1 = __builtin_amdgcn_mfma_f32_16x16x32_f16(afrag[1][0], v0, fz, 0, 0, 0);
        a2 = __builtin_amdgcn_mfma_f32_16x16x32_f16(afrag[2][0], v0, fz, 0, 0, 0);
        a3 = __builtin_amdgcn_mfma_f32_16x16x32_f16(afrag[3][0], v0, fz, 0, 0, 0);
        a0 = __builtin_amdgcn_mfma_f32_16x16x32_f16(afrag[0][1], v1, a0, 0, 0, 0);
        a1 = __builtin_amdgcn_mfma_f32_16x16x32_f16(afrag[1][1], v1, a1, 0, 0, 0);
        a2 = __builtin_amdgcn_mfma_f32_16x16x32_f16(afrag[2][1], v1, a2, 0, 0, 0);
        a3 = __builtin_amdgcn_mfma_f32_16x16x32_f16(afrag[3][1], v1, a3, 0, 0, 0);
        a0 = __builtin_amdgcn_mfma_f32_16x16x32_f16(afrag[0][2], v2, a0, 0, 0, 0);
        a1 = __builtin_amdgcn_mfma_f32_16x16x32_f16(afrag[1][2], v2, a1, 0, 0, 0);
        a2 = __builtin_amdgcn_mfma_f32_16x16x32_f16(afrag[2][2], v2, a2, 0, 0, 0);
        a3 = __builtin_amdgcn_mfma_f32_16x16x32_f16(afrag[3][2], v2, a3, 0, 0, 0);
        a0 = __builtin_amdgcn_mfma_f32_16x16x32_f16(afrag[0][3], v3, a0, 0, 0, 0);
        a1 = __builtin_amdgcn_mfma_f32_16x16x32_f16(afrag[1][3], v3, a1, 0, 0, 0);
        a2 = __builtin_amdgcn_mfma_f32_16x16x32_f16(afrag[2][3], v3, a2, 0, 0, 0);
        a3 = __builtin_amdgcn_mfma_f32_16x16x32_f16(afrag[3][3], v3, a3, 0, 0, 0);
      }

      // ---- in-wave cell update (2 units per lane, cols 0..7) ----
      if (updlane) {
        const float4_t ga = jl ? a1 : a0;  // gates of u0 (t = jl)
        const float4_t gb = jl ? a3 : a2;  // gates of u1 (t = jl+2)
        const float i0 = sigf(ga[0]), f0 = sigf(ga[1]);
        const float g0 = tanh_fast(ga[2]), o0 = sigf(ga[3]);
        c0 = f0 * c0 + i0 * g0;
        const float h0 = o0 * tanh_fast(c0);
        const float i1 = sigf(gb[0]), f1 = sigf(gb[1]);
        const float g1 = tanh_fast(gb[2]), o1 = sigf(gb[3]);
        c1 = f1 * c1 + i1 * g1;
        const float h1 = o1 * tanh_fast(c1);
        const half2_t hv = {(half_t)h0, (half_t)h1};
        half_t* ownp = &Bbuf[glay][par ^ 1][bb][SEC_OWN + sbase];
        *(half2_t*)ownp = hv;
        *(half2_t*)(ownp + 4 * KP) = hv;
        if (glay < NL - 1) {
          half_t* nxt = &Bbuf[glay + 1][par][bb][sbase];
          *(half2_t*)nxt = hv;
          *(half2_t*)(nxt + 4 * KP) = hv;
        } else if (t == TT - 1) {
          fc_h[bb][u0] = h0;
          if (u1 < H) fc_h[bb][u1] = h1;
        }
      }
    }

    // commit prefetched x for t = s+1 (parity (s+1)&1)
    if (xact && (s + 1) < TT) {
      const half_t xh = (half_t)xv;
      Bbuf[0][(s + 1) & 1][xb][xk] = xh;
      Bbuf[0][(s + 1) & 1][xb + 4][xk] = xh;
    }
    __syncthreads();
  }

  // ---- FC head (fp32) ----
  if (tid < BPG * FC1N) {
    const int b = tid / FC1N, j = tid % FC1N;
    const float* w = p.W1 + j * H;
    float a = p.b1[j];
#pragma unroll
    for (int k = 0; k < H; ++k) a += fc_h[b][k] * w[k];
    fc1_buf[b][j] = fmaxf(a, 0.0f);
  }
  __syncthreads();
  if (tid < BPG) {
    float a = p.b2[0];
#pragma unroll
    for (int j = 0; j < FC1N; ++j) a += fc1_buf[tid][j] * p.W2[j];
    p.out[b0 + tid] = a;
  }
}

extern "C" void kernel_launch(void* const* d_in, const int* in_sizes, int n_in,
                              void* d_out, int out_size, void* d_ws, size_t ws_size,
                              hipStream_t stream) {
  Params p;
  p.x = (const float*)d_in[0];
  for (int l = 0; l < NL; ++l) {
    p.Wih[l] = (const float*)d_in[1 + 4 * l];
    p.Whh[l] = (const float*)d_in[2 + 4 * l];
    p.bih[l] = (const float*)d_in[3 + 4 * l];
    p.bhh[l] = (const float*)d_in[4 + 4 * l];
  }
  p.W1 = (const float*)d_in[17];
  p.b1 = (const float*)d_in[18];
  p.W2 = (const float*)d_in[19];
  p.b2 = (const float*)d_in[20];
  p.out = (float*)d_out;

  hipLaunchKernelGGL(lstm_r3, dim3(NBLK), dim3(NTHREADS), 0, stream, p);
}

// Round 4
// 725.762 us; speedup vs baseline: 2.1569x; 1.3867x over previous
//
#include <hip/hip_runtime.h>

// LSTMModel: 4-layer LSTM (H=50, IN=7, B=1024, T=512) + FC(50->25 relu ->1).
// R4: R3 skeleton (1 barrier/tick, in-wave update, weights resident as MFMA
// A-fragments) with the VALU issue fixed:
//  - sigmoid/tanh via raw v_rcp_f32 + v_exp_f32 (no IEEE div sequences)
//  - 4x batch replication in B cols: 16 cols = 4 batches x 4 replicas, each
//    lane updates exactly ONE unit (t-tile = col>>2) -> 10 trans ops/wave
//    instead of 20, all 64 lanes carry work, identity slot map (scalar b16
//    h-writes to the 4 replica rows).
//  - skip empty M-tiles (wl==3, t>=1) and layer-0's zero K-group.
// B layout per layer/parity: rows 0..15 = batch(b=row&3) replica(row>>2),
// slots: [0..49]=input-h (l>=1) or [0..6]=x (l=0), bias-1.0 at slot 7 (l=0)
// or 56 (l>=1), [64..113]=own-h. Parity-double-buffered; gates row r=4u+q.

#define H 50
#define INSZ 7
#define BATCH 1024
#define TT 512
#define NL 4
#define FC1N 25
#define BPG 4
#define NBLK (BATCH / BPG)
#define NTHREADS 1024
#define KP 136        // Bbuf row stride in halves (272 B)
#define ROWS 16
#define SEC_OWN 64
#define BIAS0 7
#define BIASL 56

typedef _Float16 half_t;
typedef __attribute__((ext_vector_type(8))) _Float16 half8_t;
typedef __attribute__((ext_vector_type(4))) float float4_t;

struct Params {
  const float* x;
  const float* Wih[NL];
  const float* Whh[NL];
  const float* bih[NL];
  const float* bhh[NL];
  const float* W1;
  const float* b1;
  const float* W2;
  const float* b2;
  float* out;
};

__device__ __forceinline__ float fast_rcp(float x) {
#if __has_builtin(__builtin_amdgcn_rcpf)
  return __builtin_amdgcn_rcpf(x);
#else
  return 1.0f / x;
#endif
}
__device__ __forceinline__ float fast_exp2(float x) {
#if __has_builtin(__builtin_amdgcn_exp2f)
  return __builtin_amdgcn_exp2f(x);
#else
  return exp2f(x);
#endif
}
// sigmoid(x) = 1/(1+e^-x); e^-x = 2^(-x*log2e). Saturates cleanly (inf->0).
__device__ __forceinline__ float sigf(float x) {
  return fast_rcp(1.0f + fast_exp2(-1.442695041f * x));
}
__device__ __forceinline__ float tanh_fast(float x) {
  return 2.0f * fast_rcp(1.0f + fast_exp2(-2.885390082f * x)) - 1.0f;
}

__global__ __launch_bounds__(NTHREADS, 4) void lstm_r4(Params p) {
  __shared__ __align__(16) half_t Bbuf[NL][2][ROWS][KP];
  __shared__ float fc_h[BPG][H];
  __shared__ float fc1_buf[BPG][FC1N];

  const int tid = threadIdx.x;
  const int b0 = blockIdx.x * BPG;
  const int lane = tid & 63;
  const int quad = lane >> 4;
  const int col = lane & 15;
  const int glay = tid >> 8;       // 4 waves per layer
  const int wl = (tid >> 6) & 3;   // wave within layer (M-chunk of 64 rows)

  // ---- A fragments (weights + bias column), resident in VGPRs/AGPRs ----
  // A[m][k]: m = col -> gate row r = wl*64 + t*16 + col (rows unit-major
  // r = 4u+q), k = g*32 + quad*8 + j. Identity slot->unit map.
  half8_t afrag[4][4];
#pragma unroll
  for (int t = 0; t < 4; ++t) {
#pragma unroll
    for (int g = 0; g < 4; ++g) {
      half8_t v;
#pragma unroll
      for (int j = 0; j < 8; ++j) {
        const int r = wl * 64 + t * 16 + col;
        const int u = r >> 2, q = r & 3;
        const int k = g * 32 + quad * 8 + j;
        float wv = 0.0f;
        if (u < H) {
          const int row = q * H + u;
          if (glay == 0) {
            if (k < INSZ) wv = p.Wih[0][row * INSZ + k];
            else if (k == BIAS0) wv = p.bih[0][row] + p.bhh[0][row];
            else if (k >= SEC_OWN && (k - SEC_OWN) < H) wv = p.Whh[0][row * H + (k - SEC_OWN)];
          } else {
            if (k < H) wv = p.Wih[glay][row * H + k];
            else if (k == BIASL) wv = p.bih[glay][row] + p.bhh[glay][row];
            else if (k >= SEC_OWN && (k - SEC_OWN) < H) wv = p.Whh[glay][row * H + (k - SEC_OWN)];
          }
        }
        v[j] = (half_t)wv;
      }
      afrag[t][g] = v;
    }
  }

  // ---- zero Bbuf, set bias slots, preload x(t=0) into 4 replica rows ----
  {
    unsigned* bz = (unsigned*)Bbuf;
    const int nw = (int)(NL * 2 * ROWS * KP / 2);
    for (int i = tid; i < nw; i += NTHREADS) bz[i] = 0u;
  }
  __syncthreads();
  if (tid < 128) {  // 4 layers x 2 parities x 16 rows
    const int l = tid >> 5, pp = (tid >> 4) & 1, row = tid & 15;
    Bbuf[l][pp][row][(l == 0) ? BIAS0 : BIASL] = (half_t)1.0f;
  }
  if (tid >= 128 && tid < 128 + BPG * INSZ) {
    const int idx = tid - 128, b = idx / INSZ, k = idx % INSZ;
    const half_t xh = (half_t)p.x[((size_t)(b0 + b) * TT + 0) * INSZ + k];
    Bbuf[0][0][b][k] = xh;
    Bbuf[0][0][b + 4][k] = xh;
    Bbuf[0][0][b + 8][k] = xh;
    Bbuf[0][0][b + 12][k] = xh;
  }
  __syncthreads();

  // ---- per-lane roles ----
  const int tsel = col >> 2;               // which t-tile this lane updates
  const int bb = col & 3;                  // batch
  const int uu = 16 * wl + 4 * tsel + quad;  // unit
  const bool updact = (uu < H);

  // x prefetch: wave (glay=0, wl=3), lanes 32..59 (all update-inactive there)
  const int xidx = lane - 32;
  const bool xact = (glay == 0) && (wl == 3) && (xidx >= 0) && (xidx < BPG * INSZ);
  const int xb = xact ? xidx / INSZ : 0;
  const int xk = xact ? xidx % INSZ : 0;

  const half_t* bp[2] = {&Bbuf[glay][0][col][0], &Bbuf[glay][1][col][0]};

  float cst = 0.0f;
  const float4_t fz = {0.0f, 0.0f, 0.0f, 0.0f};

  // ---- main loop: one barrier per tick ----
  for (int s = 0; s < TT + NL - 1; ++s) {
    const int t = s - glay;
    const bool act = (t >= 0) && (t < TT);

    float xv = 0.0f;
    if (xact && (s + 1) < TT)
      xv = p.x[((size_t)(b0 + xb) * TT + (s + 1)) * INSZ + xk];

    if (act) {
      const int par = t & 1;
      const half_t* base = bp[par];
      float4_t acc[4] = {fz, fz, fz, fz};
#pragma unroll
      for (int g = 0; g < 4; ++g) {
        if (glay == 0 && g == 1) continue;  // layer0: K 32..63 is all-zero
        const half8_t bv = *(const half8_t*)(base + g * 32 + quad * 8);
#pragma unroll
        for (int t4 = 0; t4 < 4; ++t4) {
          if (16 * wl + 4 * t4 < H)  // skip all-pad M-tiles (wl==3, t4>=1)
            acc[t4] = __builtin_amdgcn_mfma_f32_16x16x32_f16(afrag[t4][g], bv, acc[t4], 0, 0, 0);
        }
      }

      // ---- in-wave cell update: 1 unit per lane ----
      if (updact) {
        const float4_t g01 = (col & 4) ? acc[1] : acc[0];
        const float4_t g23 = (col & 4) ? acc[3] : acc[2];
        const float4_t ga = (col & 8) ? g23 : g01;
        const float gi = sigf(ga[0]);
        const float gf = sigf(ga[1]);
        const float gg = tanh_fast(ga[2]);
        const float go = sigf(ga[3]);
        cst = gf * cst + gi * gg;
        const float h = go * tanh_fast(cst);
        const half_t hh = (half_t)h;
        half_t* ownp = &Bbuf[glay][par ^ 1][bb][SEC_OWN + uu];
        ownp[0] = hh;
        ownp[4 * KP] = hh;
        ownp[8 * KP] = hh;
        ownp[12 * KP] = hh;
        if (glay < NL - 1) {
          half_t* nx = &Bbuf[glay + 1][par][bb][uu];
          nx[0] = hh;
          nx[4 * KP] = hh;
          nx[8 * KP] = hh;
          nx[12 * KP] = hh;
        } else if (t == TT - 1) {
          fc_h[bb][uu] = h;
        }
      }
    }

    // commit prefetched x for t = s+1 into parity (s+1)&1, 4 replica rows
    if (xact && (s + 1) < TT) {
      const half_t xh = (half_t)xv;
      half_t* xp = &Bbuf[0][(s + 1) & 1][xb][xk];
      xp[0] = xh;
      xp[4 * KP] = xh;
      xp[8 * KP] = xh;
      xp[12 * KP] = xh;
    }
    __syncthreads();
  }

  // ---- FC head (fp32) ----
  if (tid < BPG * FC1N) {
    const int b = tid / FC1N, j = tid % FC1N;
    const float* w = p.W1 + j * H;
    float a = p.b1[j];
#pragma unroll
    for (int k = 0; k < H; ++k) a += fc_h[b][k] * w[k];
    fc1_buf[b][j] = fmaxf(a, 0.0f);
  }
  __syncthreads();
  if (tid < BPG) {
    float a = p.b2[0];
#pragma unroll
    for (int j = 0; j < FC1N; ++j) a += fc1_buf[tid][j] * p.W2[j];
    p.out[b0 + tid] = a;
  }
}

extern "C" void kernel_launch(void* const* d_in, const int* in_sizes, int n_in,
                              void* d_out, int out_size, void* d_ws, size_t ws_size,
                              hipStream_t stream) {
  Params p;
  p.x = (const float*)d_in[0];
  for (int l = 0; l < NL; ++l) {
    p.Wih[l] = (const float*)d_in[1 + 4 * l];
    p.Whh[l] = (const float*)d_in[2 + 4 * l];
    p.bih[l] = (const float*)d_in[3 + 4 * l];
    p.bhh[l] = (const float*)d_in[4 + 4 * l];
  }
  p.W1 = (const float*)d_in[17];
  p.b1 = (const float*)d_in[18];
  p.W2 = (const float*)d_in[19];
  p.b2 = (const float*)d_in[20];
  p.out = (float*)d_out;

  hipLaunchKernelGGL(lstm_r4, dim3(NBLK), dim3(NTHREADS), 0, stream, p);
}

// Round 5
// 574.551 us; speedup vs baseline: 2.7245x; 1.2632x over previous
//
#include <hip/hip_runtime.h>

// LSTMModel: 4-layer LSTM (H=50, IN=7, B=1024, T=512) + FC(50->25 relu ->1).
// R5: R4 structure (1 barrier/tick, in-wave update, resident A-frags) minus
// the replica-write waste:
//  - B-frag READ row = col&3 (LDS broadcast, free) -> no replica writes.
//  - layer l+1 reads input-h from layer l's own-h section at parity (t+1)&1
//    (race-free: l writes the other parity) -> no next-layer store.
//  => 1 b16 h-store per update lane (was 8), x written once (was 4).
//  - row stride 80 halves (40 dw = 8 mod 32): b128 reads <=2-way (free),
//    h-stores hit 32 distinct banks.
//  - wl = (waveid + layer) & 3: each SIMD gets one light wl=3 wave.
//  - parity-indexed precomputed pointers (2 copies + cndmask) for all LDS addrs.
// Sections: Hbuf[l][par][b][80]: h at slots 0..49, bias-1.0 at 56 (read as
// input by layer l+1 whose A has bias col at k=56; own view k=120 -> A=0).
// Xbuf[par][b][80]: x at 0..6, bias-1.0 at 7 (layer0's A bias col at k=7).

#define H 50
#define INSZ 7
#define BATCH 1024
#define TT 512
#define NL 4
#define FC1N 25
#define BPG 4
#define NBLK (BATCH / BPG)
#define NTHREADS 1024
#define HS 80        // row stride in halves (160 B, 40 dw = 8 mod 32)
#define BIAS0 7
#define BIASL 56

typedef _Float16 half_t;
typedef __attribute__((ext_vector_type(8))) _Float16 half8_t;
typedef __attribute__((ext_vector_type(4))) float float4_t;

struct Params {
  const float* x;
  const float* Wih[NL];
  const float* Whh[NL];
  const float* bih[NL];
  const float* bhh[NL];
  const float* W1;
  const float* b1;
  const float* W2;
  const float* b2;
  float* out;
};

__device__ __forceinline__ float fast_rcp(float x) {
  return __builtin_amdgcn_rcpf(x);
}
__device__ __forceinline__ float fast_exp2(float x) {
  return __builtin_amdgcn_exp2f(x);
}
__device__ __forceinline__ float sigf(float x) {
  return fast_rcp(1.0f + fast_exp2(-1.442695041f * x));
}
__device__ __forceinline__ float tanh_fast(float x) {
  return 2.0f * fast_rcp(1.0f + fast_exp2(-2.885390082f * x)) - 1.0f;
}

__global__ __launch_bounds__(NTHREADS, 4) void lstm_r5(Params p) {
  __shared__ __align__(16) half_t Hbuf[NL][2][BPG][HS];  // own-h per layer/parity
  __shared__ __align__(16) half_t Xbuf[2][BPG][HS];      // x per parity
  __shared__ float fc_h[BPG][H];
  __shared__ float fc1_buf[BPG][FC1N];

  const int tid = threadIdx.x;
  const int b0 = blockIdx.x * BPG;
  const int lane = tid & 63;
  const int quad = lane >> 4;
  const int col = lane & 15;
  const int glay = tid >> 8;                    // layer (4 waves each)
  const int wl = (((tid >> 6) & 3) + glay) & 3; // M-chunk, SIMD-balanced

  // ---- A fragments: A[m=col -> row r=wl*64+t4*16+col][k=g*32+quad*8+j] ----
  // rows unit-major r=4u+q; k<64 = input section, k>=64 = own-h section.
  half8_t afrag[4][4];
#pragma unroll
  for (int t4 = 0; t4 < 4; ++t4) {
#pragma unroll
    for (int g = 0; g < 4; ++g) {
      half8_t v;
#pragma unroll
      for (int j = 0; j < 8; ++j) {
        const int r = wl * 64 + t4 * 16 + col;
        const int u = r >> 2, q = r & 3;
        const int k = g * 32 + quad * 8 + j;
        float wv = 0.0f;
        if (u < H) {
          const int row = q * H + u;
          if (glay == 0) {
            if (k < INSZ) wv = p.Wih[0][row * INSZ + k];
            else if (k == BIAS0) wv = p.bih[0][row] + p.bhh[0][row];
            else if (k >= 64 && (k - 64) < H) wv = p.Whh[0][row * H + (k - 64)];
          } else {
            if (k < H) wv = p.Wih[glay][row * H + k];
            else if (k == BIASL) wv = p.bih[glay][row] + p.bhh[glay][row];
            else if (k >= 64 && (k - 64) < H) wv = p.Whh[glay][row * H + (k - 64)];
          }
        }
        v[j] = (half_t)wv;
      }
      afrag[t4][g] = v;
    }
  }

  // ---- init LDS: zero, bias slots (both parities), x(t=0) ----
  {
    unsigned* hz = (unsigned*)Hbuf;
    const int nh = NL * 2 * BPG * HS / 2;
    for (int i = tid; i < nh; i += NTHREADS) hz[i] = 0u;
    unsigned* xz = (unsigned*)Xbuf;
    const int nx = 2 * BPG * HS / 2;
    for (int i = tid; i < nx; i += NTHREADS) xz[i] = 0u;
  }
  __syncthreads();
  if (tid < 32) {  // Hbuf bias: 4 layers x 2 parities x 4 batches
    const int l = tid >> 3, pr = (tid >> 2) & 1, b = tid & 3;
    Hbuf[l][pr][b][BIASL] = (half_t)1.0f;
  } else if (tid < 40) {  // Xbuf bias
    const int idx = tid - 32;
    Xbuf[idx >> 2][idx & 3][BIAS0] = (half_t)1.0f;
  }
  if (tid >= 64 && tid < 64 + BPG * INSZ) {
    const int idx = tid - 64, b = idx / INSZ, k = idx % INSZ;
    Xbuf[0][b][k] = (half_t)p.x[((size_t)(b0 + b) * TT + 0) * INSZ + k];
  }
  __syncthreads();

  // ---- per-lane roles & parity-indexed pointers ----
  const int bb = col & 3;
  const int tsel = col >> 2;
  const int uu = 16 * wl + 4 * tsel + quad;
  const bool updact = (uu < H);

  // input section read base, indexed by par = t&1:
  //   layer0: Xbuf[par];  layer>=1: Hbuf[glay-1][par^1] (holds h_{l-1}(t))
  const half_t* inb[2];
  inb[0] = (glay == 0) ? &Xbuf[0][bb][quad * 8] : &Hbuf[glay - 1][1][bb][quad * 8];
  inb[1] = (glay == 0) ? &Xbuf[1][bb][quad * 8] : &Hbuf[glay - 1][0][bb][quad * 8];
  const half_t* ownb[2] = {&Hbuf[glay][0][bb][quad * 8], &Hbuf[glay][1][bb][quad * 8]};
  half_t* stb[2] = {&Hbuf[glay][1][bb][uu], &Hbuf[glay][0][bb][uu]};  // write par^1

  // x prefetch: layer-0's wl==3 wave, lanes 32..59
  const int xidx = lane - 32;
  const bool xact = (glay == 0) && (wl == 3) && (xidx >= 0) && (xidx < BPG * INSZ);
  const int xb = xact ? xidx / INSZ : 0;
  const int xk = xact ? xidx % INSZ : 0;

  float cst = 0.0f;
  const float4_t fz = {0.0f, 0.0f, 0.0f, 0.0f};

  // ---- main loop: one barrier per tick ----
  for (int s = 0; s < TT + NL - 1; ++s) {
    const int t = s - glay;
    const bool act = (t >= 0) && (t < TT);

    float xv = 0.0f;
    if (xact && (s + 1) < TT)
      xv = p.x[((size_t)(b0 + xb) * TT + (s + 1)) * INSZ + xk];

    if (act) {
      const int par = t & 1;
      const half_t* pin = inb[par];
      const half_t* pow_ = ownb[par];
      float4_t a0 = fz, a1 = fz, a2 = fz, a3 = fz;

      if (glay == 0) {
        const half8_t v0 = *(const half8_t*)(pin);
        const half8_t v2 = *(const half8_t*)(pow_);
        const half8_t v3 = *(const half8_t*)(pow_ + 32);
        a0 = __builtin_amdgcn_mfma_f32_16x16x32_f16(afrag[0][0], v0, a0, 0, 0, 0);
        a1 = __builtin_amdgcn_mfma_f32_16x16x32_f16(afrag[1][0], v0, a1, 0, 0, 0);
        a2 = __builtin_amdgcn_mfma_f32_16x16x32_f16(afrag[2][0], v0, a2, 0, 0, 0);
        if (16 * wl < H - 48) {} // placeholder no-op for symmetry
        a3 = __builtin_amdgcn_mfma_f32_16x16x32_f16(afrag[3][0], v0, a3, 0, 0, 0);
        a0 = __builtin_amdgcn_mfma_f32_16x16x32_f16(afrag[0][2], v2, a0, 0, 0, 0);
        a1 = __builtin_amdgcn_mfma_f32_16x16x32_f16(afrag[1][2], v2, a1, 0, 0, 0);
        a2 = __builtin_amdgcn_mfma_f32_16x16x32_f16(afrag[2][2], v2, a2, 0, 0, 0);
        a3 = __builtin_amdgcn_mfma_f32_16x16x32_f16(afrag[3][2], v2, a3, 0, 0, 0);
        a0 = __builtin_amdgcn_mfma_f32_16x16x32_f16(afrag[0][3], v3, a0, 0, 0, 0);
        a1 = __builtin_amdgcn_mfma_f32_16x16x32_f16(afrag[1][3], v3, a1, 0, 0, 0);
        a2 = __builtin_amdgcn_mfma_f32_16x16x32_f16(afrag[2][3], v3, a2, 0, 0, 0);
        a3 = __builtin_amdgcn_mfma_f32_16x16x32_f16(afrag[3][3], v3, a3, 0, 0, 0);
      } else {
        const half8_t v0 = *(const half8_t*)(pin);
        const half8_t v1 = *(const half8_t*)(pin + 32);
        const half8_t v2 = *(const half8_t*)(pow_);
        const half8_t v3 = *(const half8_t*)(pow_ + 32);
        if (wl != 3) {
          a0 = __builtin_amdgcn_mfma_f32_16x16x32_f16(afrag[0][0], v0, a0, 0, 0, 0);
          a1 = __builtin_amdgcn_mfma_f32_16x16x32_f16(afrag[1][0], v0, a1, 0, 0, 0);
          a2 = __builtin_amdgcn_mfma_f32_16x16x32_f16(afrag[2][0], v0, a2, 0, 0, 0);
          a3 = __builtin_amdgcn_mfma_f32_16x16x32_f16(afrag[3][0], v0, a3, 0, 0, 0);
          a0 = __builtin_amdgcn_mfma_f32_16x16x32_f16(afrag[0][1], v1, a0, 0, 0, 0);
          a1 = __builtin_amdgcn_mfma_f32_16x16x32_f16(afrag[1][1], v1, a1, 0, 0, 0);
          a2 = __builtin_amdgcn_mfma_f32_16x16x32_f16(afrag[2][1], v1, a2, 0, 0, 0);
          a3 = __builtin_amdgcn_mfma_f32_16x16x32_f16(afrag[3][1], v1, a3, 0, 0, 0);
          a0 = __builtin_amdgcn_mfma_f32_16x16x32_f16(afrag[0][2], v2, a0, 0, 0, 0);
          a1 = __builtin_amdgcn_mfma_f32_16x16x32_f16(afrag[1][2], v2, a1, 0, 0, 0);
          a2 = __builtin_amdgcn_mfma_f32_16x16x32_f16(afrag[2][2], v2, a2, 0, 0, 0);
          a3 = __builtin_amdgcn_mfma_f32_16x16x32_f16(afrag[3][2], v2, a3, 0, 0, 0);
          a0 = __builtin_amdgcn_mfma_f32_16x16x32_f16(afrag[0][3], v3, a0, 0, 0, 0);
          a1 = __builtin_amdgcn_mfma_f32_16x16x32_f16(afrag[1][3], v3, a1, 0, 0, 0);
          a2 = __builtin_amdgcn_mfma_f32_16x16x32_f16(afrag[2][3], v3, a2, 0, 0, 0);
          a3 = __builtin_amdgcn_mfma_f32_16x16x32_f16(afrag[3][3], v3, a3, 0, 0, 0);
        } else {  // wl==3: only t4=0 tile valid (units 48,49)
          a0 = __builtin_amdgcn_mfma_f32_16x16x32_f16(afrag[0][0], v0, a0, 0, 0, 0);
          a0 = __builtin_amdgcn_mfma_f32_16x16x32_f16(afrag[0][1], v1, a0, 0, 0, 0);
          a0 = __builtin_amdgcn_mfma_f32_16x16x32_f16(afrag[0][2], v2, a0, 0, 0, 0);
          a0 = __builtin_amdgcn_mfma_f32_16x16x32_f16(afrag[0][3], v3, a0, 0, 0, 0);
        }
      }
      // layer0 wl==3 also only needs a0, but uniform code above is harmless.

      // ---- in-wave cell update: 1 (unit,batch) per lane, no duplication ----
      if (updact) {
        const float4_t g01 = (col & 4) ? a1 : a0;
        const float4_t g23 = (col & 4) ? a3 : a2;
        const float4_t ga = (col & 8) ? g23 : g01;
        const float gi = sigf(ga[0]);
        const float gf = sigf(ga[1]);
        const float gg = tanh_fast(ga[2]);
        const float go = sigf(ga[3]);
        cst = gf * cst + gi * gg;
        const float h = go * tanh_fast(cst);
        *(stb[par]) = (half_t)h;                 // single b16 store
        if (glay == NL - 1 && t == TT - 1) fc_h[bb][uu] = h;
      }
    }

    if (xact && (s + 1) < TT)
      Xbuf[(s + 1) & 1][xb][xk] = (half_t)xv;
    __syncthreads();
  }

  // ---- FC head (fp32) ----
  if (tid < BPG * FC1N) {
    const int b = tid / FC1N, j = tid % FC1N;
    const float* w = p.W1 + j * H;
    float a = p.b1[j];
#pragma unroll
    for (int k = 0; k < H; ++k) a += fc_h[b][k] * w[k];
    fc1_buf[b][j] = fmaxf(a, 0.0f);
  }
  __syncthreads();
  if (tid < BPG) {
    float a = p.b2[0];
#pragma unroll
    for (int j = 0; j < FC1N; ++j) a += fc1_buf[tid][j] * p.W2[j];
    p.out[b0 + tid] = a;
  }
}

extern "C" void kernel_launch(void* const* d_in, const int* in_sizes, int n_in,
                              void* d_out, int out_size, void* d_ws, size_t ws_size,
                              hipStream_t stream) {
  Params p;
  p.x = (const float*)d_in[0];
  for (int l = 0; l < NL; ++l) {
    p.Wih[l] = (const float*)d_in[1 + 4 * l];
    p.Whh[l] = (const float*)d_in[2 + 4 * l];
    p.bih[l] = (const float*)d_in[3 + 4 * l];
    p.bhh[l] = (const float*)d_in[4 + 4 * l];
  }
  p.W1 = (const float*)d_in[17];
  p.b1 = (const float*)d_in[18];
  p.W2 = (const float*)d_in[19];
  p.b2 = (const float*)d_in[20];
  p.out = (float*)d_out;

  hipLaunchKernelGGL(lstm_r5, dim3(NBLK), dim3(NTHREADS), 0, stream, p);
}

// Round 6
// 489.654 us; speedup vs baseline: 3.1969x; 1.1734x over previous
//
#include <hip/hip_runtime.h>

// LSTMModel: 4-layer LSTM (H=50, IN=7, B=1024, T=512) + FC(50->25 relu ->1).
// R6: R5 skeleton (1 barrier/tick, in-wave update, resident A-frags, broadcast
// B-reads, single h-store) plus:
//  - x staged via 64-slot LDS ring (Xstage[64][4][32] halves), refilled 32
//    timesteps per burst every 32 ticks by the layer-0 wl==3 wave. Steady
//    ticks have NO outstanding global loads at the barrier (no vmcnt drain).
//  - steady loop s=3..510 unrolled x2: compile-time parity per half, all
//    parity-selected pointers hoisted; no act/t guards in steady state.
//  - layer-0 bias at own-section slot 56 (const-1.0 in Hbuf[0], k=120) so
//    ring rows are pure x; layer-0 wl==3 wave runs 3 MFMAs only.
// Layout: Hbuf[l][par][b][80]: h at 0..49, const-1.0 at 56 (doubles as bias
// input for layer l+1 at k=56 and own bias for layer 0 at k=120).
// Xstage row: x at 0..6, slots 7..31 zero (A is zero there; keeps MFMA NaN-free).

#define H 50
#define INSZ 7
#define TT 512
#define NL 4
#define FC1N 25
#define BPG 4
#define NBLK 256
#define NTHREADS 1024
#define HS 80         // Hbuf row stride in halves (40 dw = 8 mod 32: 2-way max)
#define BIASL 56
#define XRING 64
#define XB 32         // Xstage per-b stride in halves

typedef _Float16 half_t;
typedef __attribute__((ext_vector_type(8))) _Float16 half8_t;
typedef __attribute__((ext_vector_type(4))) float float4_t;

struct Params {
  const float* x;
  const float* Wih[NL];
  const float* Whh[NL];
  const float* bih[NL];
  const float* bhh[NL];
  const float* W1;
  const float* b1;
  const float* W2;
  const float* b2;
  float* out;
};

__device__ __forceinline__ float sigf(float x) {
  return __builtin_amdgcn_rcpf(1.0f + __builtin_amdgcn_exp2f(-1.442695041f * x));
}
__device__ __forceinline__ float tanh_fast(float x) {
  return 2.0f * __builtin_amdgcn_rcpf(1.0f + __builtin_amdgcn_exp2f(-2.885390082f * x)) - 1.0f;
}

#define MFMA16(A, B, C) __builtin_amdgcn_mfma_f32_16x16x32_f16((A), (B), (C), 0, 0, 0)

__global__ __launch_bounds__(NTHREADS, 4) void lstm_r6(Params p) {
  __shared__ __align__(16) half_t Hbuf[NL][2][BPG][HS];
  __shared__ __align__(16) half_t Xstage[XRING][BPG][XB];  // 16 KB ring
  __shared__ float fc_h[BPG][H];
  __shared__ float fc1_buf[BPG][FC1N];

  const int tid = threadIdx.x;
  const int b0 = blockIdx.x * BPG;
  const int lane = tid & 63;
  const int quad = lane >> 4;
  const int col = lane & 15;
  const int glay = tid >> 8;                     // layer (4 waves each)
  const int wl = (((tid >> 6) & 3) + glay) & 3;  // M-chunk, SIMD-balanced

  // ---- A fragments: row r = wl*64 + t4*16 + col (unit-major r=4u+q),
  //      k = g*32 + quad*8 + j. Layer0: x at k<7, own-h at 64..113, bias k=120.
  //      Layers>=1: in-h k<50, bias k=56, own-h k=64..113.
  half8_t afrag[4][4];
#pragma unroll
  for (int t4 = 0; t4 < 4; ++t4) {
#pragma unroll
    for (int g = 0; g < 4; ++g) {
      half8_t v;
#pragma unroll
      for (int j = 0; j < 8; ++j) {
        const int r = wl * 64 + t4 * 16 + col;
        const int u = r >> 2, q = r & 3;
        const int k = g * 32 + quad * 8 + j;
        float wv = 0.0f;
        if (u < H) {
          const int row = q * H + u;
          if (glay == 0) {
            if (k < INSZ) wv = p.Wih[0][row * INSZ + k];
            else if (k >= 64 && (k - 64) < H) wv = p.Whh[0][row * H + (k - 64)];
            else if (k == 120) wv = p.bih[0][row] + p.bhh[0][row];
          } else {
            if (k < H) wv = p.Wih[glay][row * H + k];
            else if (k == BIASL) wv = p.bih[glay][row] + p.bhh[glay][row];
            else if (k >= 64 && (k - 64) < H) wv = p.Whh[glay][row * H + (k - 64)];
          }
        }
        v[j] = (half_t)wv;
      }
      afrag[t4][g] = v;
    }
  }

  // ---- init LDS ----
  {
    unsigned* hz = (unsigned*)Hbuf;
    const int nh = NL * 2 * BPG * HS / 2;
    for (int i = tid; i < nh; i += NTHREADS) hz[i] = 0u;
    unsigned* xz = (unsigned*)Xstage;
    const int nx = XRING * BPG * XB / 2;
    for (int i = tid; i < nx; i += NTHREADS) xz[i] = 0u;
  }
  __syncthreads();
  if (tid < 32) {  // Hbuf const-1.0: 4 layers x 2 parities x 4 batches, slot 56
    const int l = tid >> 3, pr = (tid >> 2) & 1, b = tid & 3;
    Hbuf[l][pr][b][BIASL] = (half_t)1.0f;
  }
  // initial ring fill: t = 0..63
  for (int i = tid; i < XRING * BPG * INSZ; i += NTHREADS) {
    const int t = i / (BPG * INSZ), rem = i % (BPG * INSZ);
    const int b = rem / INSZ, k = rem % INSZ;
    Xstage[t][b][k] = (half_t)p.x[((size_t)(b0 + b) * TT + t) * INSZ + k];
  }
  __syncthreads();

  // ---- per-lane roles ----
  const int bb = col & 3;
  const int tsel = col >> 2;
  const int uu = 16 * wl + 4 * tsel + quad;
  const bool updact = (uu < H);

  const half_t* inb[2];   // input base by par (layers>=1; layer0 uses ring)
  inb[0] = (glay == 0) ? (const half_t*)Xstage : &Hbuf[glay - 1][1][bb][quad * 8];
  inb[1] = (glay == 0) ? (const half_t*)Xstage : &Hbuf[glay - 1][0][bb][quad * 8];
  const half_t* ownb[2] = {&Hbuf[glay][0][bb][quad * 8], &Hbuf[glay][1][bb][quad * 8]};
  half_t* stb[2] = {&Hbuf[glay][1][bb][uu], &Hbuf[glay][0][bb][uu]};

  // parity constants for steady halves: par(s) = (s&1) ^ (glay&1)
  const int pe = glay & 1, po = pe ^ 1;         // par at even s / odd s
  const half_t* in_e = inb[pe];
  const half_t* in_o = inb[po];
  const half_t* own_e = ownb[pe];
  const half_t* own_o = ownb[po];
  half_t* st_e = stb[pe];
  half_t* st_o = stb[po];
  const half_t* xrb = &Xstage[0][bb][quad * 8];  // ring read base for layer 0

  // refill role: layer-0 wl==3 wave (tid 192..255 given the balance rotation)
  const bool xwave = (glay == 0) && (wl == 3);
  const int rb = lane >> 5;        // 0..1
  const int rt = lane & 31;        // trel 0..31

  float cst = 0.0f;

  // ================= tick body =================
#define TICK_BODY(PIN, POWN, PST, FCW)                                          \
  {                                                                             \
    const float4_t fz_ = {0.0f, 0.0f, 0.0f, 0.0f};                              \
    float4_t a0 = fz_, a1 = fz_, a2 = fz_, a3 = fz_;                            \
    if (glay == 0) {                                                            \
      const half8_t v0 = *(const half8_t*)(PIN);                                \
      const half8_t v2 = *(const half8_t*)(POWN);                               \
      const half8_t v3 = *(const half8_t*)((POWN) + 32);                        \
      if (wl != 3) {                                                            \
        a0 = MFMA16(afrag[0][0], v0, a0); a1 = MFMA16(afrag[1][0], v0, a1);     \
        a2 = MFMA16(afrag[2][0], v0, a2); a3 = MFMA16(afrag[3][0], v0, a3);     \
        a0 = MFMA16(afrag[0][2], v2, a0); a1 = MFMA16(afrag[1][2], v2, a1);     \
        a2 = MFMA16(afrag[2][2], v2, a2); a3 = MFMA16(afrag[3][2], v2, a3);     \
        a0 = MFMA16(afrag[0][3], v3, a0); a1 = MFMA16(afrag[1][3], v3, a1);     \
        a2 = MFMA16(afrag[2][3], v3, a2); a3 = MFMA16(afrag[3][3], v3, a3);     \
      } else {                                                                  \
        a0 = MFMA16(afrag[0][0], v0, a0);                                       \
        a0 = MFMA16(afrag[0][2], v2, a0);                                       \
        a0 = MFMA16(afrag[0][3], v3, a0);                                       \
      }                                                                         \
    } else {                                                                    \
      const half8_t v0 = *(const half8_t*)(PIN);                                \
      const half8_t v1 = *(const half8_t*)((PIN) + 32);                         \
      const half8_t v2 = *(const half8_t*)(POWN);                               \
      const half8_t v3 = *(const half8_t*)((POWN) + 32);                        \
      if (wl != 3) {                                                            \
        a0 = MFMA16(afrag[0][0], v0, a0); a1 = MFMA16(afrag[1][0], v0, a1);     \
        a2 = MFMA16(afrag[2][0], v0, a2); a3 = MFMA16(afrag[3][0], v0, a3);     \
        a0 = MFMA16(afrag[0][1], v1, a0); a1 = MFMA16(afrag[1][1], v1, a1);     \
        a2 = MFMA16(afrag[2][1], v1, a2); a3 = MFMA16(afrag[3][1], v1, a3);     \
        a0 = MFMA16(afrag[0][2], v2, a0); a1 = MFMA16(afrag[1][2], v2, a1);     \
        a2 = MFMA16(afrag[2][2], v2, a2); a3 = MFMA16(afrag[3][2], v2, a3);     \
        a0 = MFMA16(afrag[0][3], v3, a0); a1 = MFMA16(afrag[1][3], v3, a1);     \
        a2 = MFMA16(afrag[2][3], v3, a2); a3 = MFMA16(afrag[3][3], v3, a3);     \
      } else {                                                                  \
        a0 = MFMA16(afrag[0][0], v0, a0);                                       \
        a0 = MFMA16(afrag[0][1], v1, a0);                                       \
        a0 = MFMA16(afrag[0][2], v2, a0);                                       \
        a0 = MFMA16(afrag[0][3], v3, a0);                                       \
      }                                                                         \
    }                                                                           \
    if (updact) {                                                               \
      const float4_t g01 = (col & 4) ? a1 : a0;                                 \
      const float4_t g23 = (col & 4) ? a3 : a2;                                 \
      const float4_t ga = (col & 8) ? g23 : g01;                                \
      const float gi = sigf(ga[0]);                                             \
      const float gf = sigf(ga[1]);                                             \
      const float gg = tanh_fast(ga[2]);                                        \
      const float go = sigf(ga[3]);                                             \
      cst = gf * cst + gi * gg;                                                 \
      const float h = go * tanh_fast(cst);                                      \
      *(PST) = (half_t)h;                                                       \
      if (FCW) fc_h[bb][uu] = h;                                                \
    }                                                                           \
  }

  // ---- prologue: s = 0..2 (guarded) ----
  for (int s = 0; s < 3; ++s) {
    const int t = s - glay;
    if (t >= 0) {
      const int par = t & 1;
      const half_t* pin = (glay == 0) ? (xrb + (t & 63) * (BPG * XB)) : inb[par];
      TICK_BODY(pin, ownb[par], stb[par], false)
    }
    __syncthreads();
  }

  // ---- steady: s = 3..510, unrolled x2, no guards ----
  for (int s = 3; s < 511; s += 2) {
    {  // odd tick s
      const int t = s - glay;
      const half_t* pin = (glay == 0) ? (xrb + (s & 63) * (BPG * XB)) : in_o;
      TICK_BODY(pin, own_o, st_o, false)
    }
    __syncthreads();
    {  // even tick s+1
      const int s2 = s + 1;
      // ring refill: 32 timesteps, once per 32 ticks, light wave only
      if (xwave && (s2 & 31) == 8 && s2 < 480) {
        const int tb = (s2 & ~31) + 32;
#pragma unroll
        for (int pp = 0; pp < 2; ++pp) {
          const int b = rb + 2 * pp;
          const int t = tb + rt;
          const float* src = &p.x[((size_t)(b0 + b) * TT + t) * INSZ];
          half_t* dst = &Xstage[t & 63][b][0];
#pragma unroll
          for (int k = 0; k < INSZ; ++k) dst[k] = (half_t)src[k];
        }
      }
      const int t = s2 - glay;
      const half_t* pin = (glay == 0) ? (xrb + (s2 & 63) * (BPG * XB)) : in_e;
      TICK_BODY(pin, own_e, st_e, false)
    }
    __syncthreads();
  }

  // ---- tail: s = 511..514 (guarded; fc write at glay==3, t==511) ----
  for (int s = 511; s < TT + NL - 1; ++s) {
    const int t = s - glay;
    if (t < TT) {
      const int par = t & 1;
      const half_t* pin = (glay == 0) ? (xrb + (t & 63) * (BPG * XB)) : inb[par];
      const bool fcw = (glay == NL - 1) && (t == TT - 1);
      TICK_BODY(pin, ownb[par], stb[par], fcw)
    }
    __syncthreads();
  }

  // ---- FC head (fp32) ----
  if (tid < BPG * FC1N) {
    const int b = tid / FC1N, j = tid % FC1N;
    const float* w = p.W1 + j * H;
    float a = p.b1[j];
#pragma unroll
    for (int k = 0; k < H; ++k) a += fc_h[b][k] * w[k];
    fc1_buf[b][j] = fmaxf(a, 0.0f);
  }
  __syncthreads();
  if (tid < BPG) {
    float a = p.b2[0];
#pragma unroll
    for (int j = 0; j < FC1N; ++j) a += fc1_buf[tid][j] * p.W2[j];
    p.out[b0 + tid] = a;
  }
}

extern "C" void kernel_launch(void* const* d_in, const int* in_sizes, int n_in,
                              void* d_out, int out_size, void* d_ws, size_t ws_size,
                              hipStream_t stream) {
  Params p;
  p.x = (const float*)d_in[0];
  for (int l = 0; l < NL; ++l) {
    p.Wih[l] = (const float*)d_in[1 + 4 * l];
    p.Whh[l] = (const float*)d_in[2 + 4 * l];
    p.bih[l] = (const float*)d_in[3 + 4 * l];
    p.bhh[l] = (const float*)d_in[4 + 4 * l];
  }
  p.W1 = (const float*)d_in[17];
  p.b1 = (const float*)d_in[18];
  p.W2 = (const float*)d_in[19];
  p.b2 = (const float*)d_in[20];
  p.out = (float*)d_out;

  hipLaunchKernelGGL(lstm_r6, dim3(NBLK), dim3(NTHREADS), 0, stream, p);
}